// Round 6
// baseline (2662.824 us; speedup 1.0000x reference)
//
#include <hip/hip_runtime.h>
#include <hip/hip_bf16.h>

// soft(v, lam) = sign(v) * max(|v| - lam, 0)   (lam may be negative)
__device__ __forceinline__ float softt(float v, float lam){
  float t = fabsf(v) - lam;
  float sg = (v > 0.f) ? 1.f : ((v < 0.f) ? -1.f : 0.f);
  return (t > 0.f) ? sg * t : 0.f;
}

#define FMA16(acc, a4, b4) do { \
  float _a[4] = {(a4).x, (a4).y, (a4).z, (a4).w}; \
  float _b[4] = {(b4).x, (b4).y, (b4).z, (b4).w}; \
  _Pragma("unroll") for (int _i = 0; _i < 4; ++_i) \
    _Pragma("unroll") for (int _j = 0; _j < 4; ++_j) \
      acc[_i][_j] += _a[_i] * _b[_j]; \
} while (0)

// L scalar (f32 input)
__global__ void k_Lin(const float* __restrict__ Lsrc, float* __restrict__ Lb){
  Lb[0] = Lsrc[0];
}

// S[j][a] = (j==a) - (sum_c Dict[c][j]*Dict[c][a]) / L   (S symmetric, so the
// reference's .T is a no-op)
__global__ void k_prep(const float* __restrict__ D, const float* __restrict__ Lb,
                       float* __restrict__ S){
  int j = blockIdx.x, a = threadIdx.x;
  float invL = 1.0f / Lb[0];
  float acc = 0.f;
  for (int c = 0; c < 64; ++c)
    acc += D[c*256 + j] * D[c*256 + a];
  S[j*256 + a] = ((j == a) ? 1.0f : 0.0f) - acc * invL;
}

// DT[a][c] = D[c][a]
__global__ void k_transpD(const float* __restrict__ D, float* __restrict__ DT){
  int gid = blockIdx.x * 256 + threadIdx.x;     // gid = a*64 + c
  if (gid < 16384) {
    int a = gid >> 6, c = gid & 63;
    DT[gid] = D[c*256 + a];
  }
}

// ---------------------------------------------------------------------------
// Implicit-GEMM conv (NCHW, 64x64 spatial, stride 1).
// NOTE: res/out deliberately NOT __restrict__ — the residual conv is called
// with res == out (same-address read+write per thread; restrict there is UB).
// ---------------------------------------------------------------------------
template<int KS, bool RELU, bool BIAS, bool RES>
__global__ __launch_bounds__(256) void k_conv(
    const float* __restrict__ in, const float* __restrict__ w,
    const float* __restrict__ bias, const float* res,
    float* out, int Cin, int Cout)
{
  const int K = Cin * KS * KS;
  __shared__ float As[32][64];
  __shared__ float Bs[32][68];
  const int tid = threadIdx.x;
  const int m0  = blockIdx.x * 64;
  const int n0  = blockIdx.y * 64;
  const int b   = m0 >> 12;
  const int hw0 = m0 & 4095;
  const int h   = hw0 >> 6;

  const int amm  = tid & 63;
  const int akk0 = tid >> 6;
  const int bkk  = tid & 31;
  const int bnn0 = tid >> 5;
  const int mmc  = (tid & 15) * 4;
  const int nnc  = (tid >> 4) * 4;

  float acc[4][4] = {};

  for (int kt = 0; kt < K; kt += 32) {
    #pragma unroll
    for (int i = 0; i < 8; ++i) {
      int kk = akk0 + i * 4;
      int k  = kt + kk;
      float v = 0.f;
      if (KS == 3) {
        int c  = k / 9;
        int r  = k - c * 9;
        int r3 = r / 3;
        int hh = h + r3 - 1;
        int ww = amm + (r - r3 * 3) - 1;
        if ((unsigned)hh < 64u && (unsigned)ww < 64u)
          v = in[((b * Cin + c) << 12) + (hh << 6) + ww];
      } else {
        v = in[((b * Cin + (kt + kk)) << 12) + hw0 + amm];
      }
      if (RELU) v = fmaxf(v, 0.f);
      As[kk][amm] = v;
    }
    #pragma unroll
    for (int i = 0; i < 8; ++i) {
      int nn = bnn0 + i * 8;
      Bs[bkk][nn] = w[(n0 + nn) * K + kt + bkk];
    }
    __syncthreads();
    #pragma unroll
    for (int kk = 0; kk < 32; ++kk) {
      float4 a4 = *(const float4*)(&As[kk][mmc]);
      float4 b4 = *(const float4*)(&Bs[kk][nnc]);
      FMA16(acc, a4, b4);
    }
    __syncthreads();
  }

  #pragma unroll
  for (int j2 = 0; j2 < 4; ++j2) {
    int n = n0 + nnc + j2;
    float bv = 0.f;
    if (BIAS) bv = bias[n];
    int base = ((b * Cout + n) << 12) + hw0 + mmc;
    float4 o4;
    o4.x = acc[0][j2] + bv; o4.y = acc[1][j2] + bv;
    o4.z = acc[2][j2] + bv; o4.w = acc[3][j2] + bv;
    if (RES) {
      float4 r4 = *(const float4*)(res + base);
      o4.x += r4.x; o4.y += r4.y; o4.z += r4.z; o4.w += r4.w;
    }
    *(float4*)(out + base) = o4;
  }
}

// ---------------------------------------------------------------------------
// CBAM
// ---------------------------------------------------------------------------
__global__ void k_pool(const float* __restrict__ l, float* __restrict__ avg,
                       float* __restrict__ mx){
  int b = blockIdx.y, a = blockIdx.x, tid = threadIdx.x;
  const float* p = l + ((size_t)(b * 256 + a) << 12);
  float s = 0.f, m = -1e30f;
  for (int i = tid; i < 4096; i += 256) { float v = p[i]; s += v; m = fmaxf(m, v); }
  __shared__ float ss[256], sm[256];
  ss[tid] = s; sm[tid] = m; __syncthreads();
  for (int o = 128; o > 0; o >>= 1) {
    if (tid < o) { ss[tid] += ss[tid+o]; sm[tid] = fmaxf(sm[tid], sm[tid+o]); }
    __syncthreads();
  }
  if (tid == 0) { avg[b*256+a] = ss[0] * (1.f/4096.f); mx[b*256+a] = sm[0]; }
}

__global__ void k_ca(const float* __restrict__ avg, const float* __restrict__ mx,
                     const float* __restrict__ w1, const float* __restrict__ w2,
                     float* __restrict__ cscale){
  int b = blockIdx.x, tid = threadIdx.x;
  __shared__ float h[16];
  if (tid < 16) {
    float sa = 0.f, sm = 0.f;
    for (int a = 0; a < 256; ++a) {
      float w = w1[tid*256 + a];
      sa += avg[b*256 + a] * w;
      sm += mx[b*256 + a] * w;
    }
    h[tid] = fmaxf(sa, 0.f) + fmaxf(sm, 0.f);
  }
  __syncthreads();
  float s = 0.f;
  for (int j = 0; j < 16; ++j) s += h[j] * w2[tid*16 + j];
  cscale[b*256 + tid] = 1.f / (1.f + __expf(-s));
}

__global__ void k_s2(const float* __restrict__ l, const float* __restrict__ cscale,
                     float* __restrict__ s2){
  int b = blockIdx.y;
  int hw = blockIdx.x * 256 + threadIdx.x;
  const float* p  = l + (((size_t)b * 256) << 12) + hw;
  const float* cs = cscale + b * 256;
  float s = 0.f, m = -1e30f;
  for (int a = 0; a < 256; ++a) {
    float v = p[(size_t)a << 12] * cs[a];
    s += v; m = fmaxf(m, v);
  }
  s2[((b*2) << 12) + hw]   = s * (1.f/256.f);
  s2[((b*2+1) << 12) + hw] = m;
}

__global__ void k_sa(const float* __restrict__ s2, const float* __restrict__ w,
                     float* __restrict__ sa){
  int b = blockIdx.y;
  int hw = blockIdx.x * 256 + threadIdx.x;
  int h = hw >> 6, ww = hw & 63;
  float acc = 0.f;
  for (int ch = 0; ch < 2; ++ch)
    for (int dh = -1; dh <= 1; ++dh)
      for (int dw = -1; dw <= 1; ++dw) {
        int hh = h + dh, wc = ww + dw;
        if ((unsigned)hh < 64u && (unsigned)wc < 64u)
          acc += s2[((b*2+ch) << 12) + (hh << 6) + wc] * w[ch*9 + (dh+1)*3 + (dw+1)];
      }
  sa[(b << 12) + hw] = 1.f / (1.f + __expf(-acc));
}

// lam[p][a] = l[b][a][hw]*csc[b][a]*sa[b][hw]/L
__global__ void k_lam_naive(const float* __restrict__ l, const float* __restrict__ cscale,
                            const float* __restrict__ sa, const float* __restrict__ Lb,
                            float* __restrict__ lam){
  int gid = blockIdx.x * 256 + threadIdx.x;          // p*256 + a
  if (gid >= 8388608) return;
  float invL = 1.0f / Lb[0];
  int a  = gid & 255;
  int p  = gid >> 8;
  int b  = p >> 12;
  int hw = p & 4095;
  float v = l[((size_t)(b*256 + a) << 12) + hw] * cscale[b*256 + a]
          * sa[(b << 12) + hw];
  lam[gid] = v * invL;
}

// ---------------------------------------------------------------------------
// Simple z-path
// ---------------------------------------------------------------------------
__global__ __launch_bounds__(256) void k_y_simple(
    const float* __restrict__ x, const float* __restrict__ D,
    const float* __restrict__ lam, float* __restrict__ y, float* __restrict__ z)
{
  __shared__ float xs[64][17];
  const int tid = threadIdx.x;
  const int r0  = blockIdx.x * 16;
  const int b   = r0 >> 12;
  const int hw0 = r0 & 4095;

  for (int idx = tid; idx < 1024; idx += 256) {
    int c = idx >> 4, w = idx & 15;
    xs[c][w] = x[((b * 64 + c) << 12) + hw0 + w];
  }
  __syncthreads();

  const int a = tid;
  float acc[16];
  #pragma unroll
  for (int r = 0; r < 16; ++r) acc[r] = 0.f;
  for (int c = 0; c < 64; ++c) {
    float d = D[c * 256 + a];
    #pragma unroll
    for (int r = 0; r < 16; ++r) acc[r] += xs[c][r] * d;
  }
  for (int r = 0; r < 16; ++r) {
    int off = (r0 + r) * 256 + a;
    float lm = lam[off];
    y[off] = acc[r];
    z[off] = softt(acc[r], lm);
  }
}

// One LISTA iteration, in-place: z = soft(z @ S + y/L, lam).
// Block owns 16 entire rows -> in-place safe.
__global__ __launch_bounds__(256) void k_iter_simple(
    float* __restrict__ z, const float* __restrict__ S,
    const float* __restrict__ y, const float* __restrict__ lam,
    const float* __restrict__ Lb)
{
  __shared__ float zs[16][256];
  const int tid = threadIdx.x;
  const int r0  = blockIdx.x * 16;
  const float invL = 1.0f / Lb[0];

  for (int idx = tid; idx < 4096; idx += 256) {
    int r = idx >> 8, k = idx & 255;
    zs[r][k] = z[(r0 + r) * 256 + k];
  }
  __syncthreads();

  const int a = tid;
  float acc[16];
  #pragma unroll
  for (int r = 0; r < 16; ++r) acc[r] = 0.f;
  for (int k = 0; k < 256; ++k) {
    float s = S[k * 256 + a];
    #pragma unroll
    for (int r = 0; r < 16; ++r) acc[r] += zs[r][k] * s;
  }
  for (int r = 0; r < 16; ++r) {
    int off = (r0 + r) * 256 + a;
    float v = acc[r] + y[off] * invL;
    z[off] = softt(v, lam[off]);
  }
}

// x_recon[p][c] = sum_a z[p][a] * DT[a][c]  -> f32 NCHW output
__global__ __launch_bounds__(256) void k_recon_simple(
    const float* __restrict__ z, const float* __restrict__ DT,
    float* __restrict__ out1)
{
  __shared__ float zs[16][256];
  const int tid = threadIdx.x;
  const int r0  = blockIdx.x * 16;
  const int b   = r0 >> 12;
  const int hw0 = r0 & 4095;

  for (int idx = tid; idx < 4096; idx += 256) {
    int r = idx >> 8, k = idx & 255;
    zs[r][k] = z[(r0 + r) * 256 + k];
  }
  __syncthreads();

  const int c  = tid & 63;
  const int rg = tid >> 6;
  float acc[4] = {0.f, 0.f, 0.f, 0.f};
  for (int a = 0; a < 256; ++a) {
    float d = DT[a * 64 + c];
    #pragma unroll
    for (int i = 0; i < 4; ++i) acc[i] += zs[rg + 4*i][a] * d;
  }
  #pragma unroll
  for (int i = 0; i < 4; ++i) {
    int r = rg + 4*i;
    out1[((b * 64 + c) << 12) + hw0 + r] = acc[i];
  }
}

// z [p][a] fp32 -> out0 f32 [b][a][hw]
__global__ void k_zout_f32(const float* __restrict__ z, float* __restrict__ out0){
  int gid = blockIdx.x * 256 + threadIdx.x;   // (b*256 + a)*4096 + hw
  if (gid >= 8388608) return;
  int b  = gid >> 20;
  int a  = (gid >> 12) & 255;
  int hw = gid & 4095;
  out0[gid] = z[((size_t)((b << 12) + hw)) * 256 + a];
}

// Dict passthrough -> f32 output
__global__ void k_dictout_f32(const float* __restrict__ D, float* __restrict__ out2){
  int i = blockIdx.x * 256 + threadIdx.x;
  if (i < 16384) out2[i] = D[i];
}

// ---------------------------------------------------------------------------
extern "C" void kernel_launch(void* const* d_in, const int* in_sizes, int n_in,
                              void* d_out, int out_size, void* d_ws, size_t ws_size,
                              hipStream_t stream)
{
  (void)in_sizes; (void)n_in; (void)out_size; (void)ws_size;

  // Inputs are float32 (proven: R1 all-bf16 read -> NaN, R3 autodetect -> f32
  // branch taken and finite).
  const float* x    = (const float*)d_in[0];
  const float* cw   = (const float*)d_in[1];
  const float* cb   = (const float*)d_in[2];
  const float* r1w1 = (const float*)d_in[3];
  const float* r1w2 = (const float*)d_in[4];
  const float* r2w1 = (const float*)d_in[5];
  const float* r2w2 = (const float*)d_in[6];
  const float* caw1 = (const float*)d_in[7];
  const float* caw2 = (const float*)d_in[8];
  const float* saw  = (const float*)d_in[9];
  const float* D    = (const float*)d_in[10];
  const float* Lsrc = (const float*)d_in[11];

  // workspace (floats): t aliases z (t dead before z written); y aliases l
  // (l dead after k_lam). Total ~101 MB.
  float* p = (float*)d_ws;
  float* S    = p; p += 65536;
  float* DT   = p; p += 16384;
  float* Lb   = p; p += 8;
  float* avg  = p; p += 2048;
  float* mx   = p; p += 2048;
  float* csc  = p; p += 2048;
  float* s2   = p; p += 65536;
  float* sa   = p; p += 32768;
  float* l    = p; p += 8388608;   // aliased as y after k_lam
  float* lam  = p; p += 8388608;
  float* zt   = p; p += 8388608;   // t (first 4M) then z
  float* t    = zt;
  float* z    = zt;
  float* y    = l;

  // OUTPUTS ARE FLOAT32 (the round-5 sentinel experiment proved the bf16
  // hypothesis impossible; f32 is the only consistent readback mode).
  float* out0 = (float*)d_out;               // z       [8,256,64,64]
  float* out1 = out0 + (size_t)8*256*4096;   // x_recon [8,64,64,64]
  float* out2 = out1 + (size_t)8*64*4096;    // Dict    [64,256]

  dim3 b256(256);

  k_Lin<<<dim3(1), dim3(1), 0, stream>>>(Lsrc, Lb);
  k_prep<<<dim3(256), b256, 0, stream>>>(D, Lb, S);
  k_transpD<<<dim3(64), b256, 0, stream>>>(D, DT);

  // conv trunk
  k_conv<3, false, true, false><<<dim3(512, 4), b256, 0, stream>>>(
      x, cw, cb, (const float*)nullptr, l, 64, 256);
  k_conv<3, true, false, false><<<dim3(512, 2), b256, 0, stream>>>(
      l, r1w1, (const float*)nullptr, (const float*)nullptr, t, 256, 128);
  k_conv<1, true, false, true><<<dim3(512, 4), b256, 0, stream>>>(
      t, r1w2, (const float*)nullptr, l, l, 128, 256);
  k_conv<3, true, false, false><<<dim3(512, 2), b256, 0, stream>>>(
      l, r2w1, (const float*)nullptr, (const float*)nullptr, t, 256, 128);
  k_conv<1, true, false, true><<<dim3(512, 4), b256, 0, stream>>>(
      t, r2w2, (const float*)nullptr, l, l, 128, 256);

  // CBAM
  k_pool<<<dim3(256, 8), b256, 0, stream>>>(l, avg, mx);
  k_ca<<<dim3(8), b256, 0, stream>>>(avg, mx, caw1, caw2, csc);
  k_s2<<<dim3(16, 8), b256, 0, stream>>>(l, csc, s2);
  k_sa<<<dim3(16, 8), b256, 0, stream>>>(s2, saw, sa);
  k_lam_naive<<<dim3(32768), b256, 0, stream>>>(l, csc, sa, Lb, lam);

  // LISTA
  k_y_simple<<<dim3(2048), b256, 0, stream>>>(x, D, lam, y, z);
  for (int it = 0; it < 16; ++it)
    k_iter_simple<<<dim3(2048), b256, 0, stream>>>(z, S, y, lam, Lb);

  // outputs (all float32)
  k_recon_simple<<<dim3(2048), b256, 0, stream>>>(z, DT, out1);
  k_zout_f32<<<dim3(32768), b256, 0, stream>>>(z, out0);
  k_dictout_f32<<<dim3(64), b256, 0, stream>>>(D, out2);
}

// Round 7
// 1353.935 us; speedup vs baseline: 1.9667x; 1.9667x over previous
//
#include <hip/hip_runtime.h>
#include <hip/hip_bf16.h>

typedef __attribute__((ext_vector_type(8))) short short8v;
typedef __attribute__((ext_vector_type(4))) float float4v;

__device__ __forceinline__ unsigned short f2bu(float v){
  __hip_bfloat16 h = __float2bfloat16(v);
  union { __hip_bfloat16 h; unsigned short u; } cv; cv.h = h; return cv.u;
}

// soft(v, lam) = sign(v) * max(|v| - lam, 0)   (lam may be negative)
__device__ __forceinline__ float softt(float v, float lam){
  float t = fabsf(v) - lam;
  float sg = (v > 0.f) ? 1.f : ((v < 0.f) ? -1.f : 0.f);
  return (t > 0.f) ? sg * t : 0.f;
}

#define FMA16(acc, a4, b4) do { \
  float _a[4] = {(a4).x, (a4).y, (a4).z, (a4).w}; \
  float _b[4] = {(b4).x, (b4).y, (b4).z, (b4).w}; \
  _Pragma("unroll") for (int _i = 0; _i < 4; ++_i) \
    _Pragma("unroll") for (int _j = 0; _j < 4; ++_j) \
      acc[_i][_j] += _a[_i] * _b[_j]; \
} while (0)

// L scalar (f32 input)
__global__ void k_Lin(const float* __restrict__ Lsrc, float* __restrict__ Lb){
  Lb[0] = Lsrc[0];
}

// Gram in bf16: Gb[j][a] = bf16(sum_c D[c][j]*D[c][a]).  Diagonal == 1 exactly.
__global__ void k_gram(const float* __restrict__ D, unsigned short* __restrict__ Gb){
  int j = blockIdx.x, a = threadIdx.x;
  float acc = 0.f;
  for (int c = 0; c < 64; ++c)
    acc += D[c*256 + j] * D[c*256 + a];
  Gb[j*256 + a] = f2bu(acc);
}

// DT[a][c] = D[c][a] (f32 for recon) + bf16 copy (B-fragments of y-GEMM)
__global__ void k_transpD(const float* __restrict__ D, float* __restrict__ DT,
                          unsigned short* __restrict__ DTb){
  int gid = blockIdx.x * 256 + threadIdx.x;     // gid = a*64 + c
  if (gid < 16384) {
    int a = gid >> 6, c = gid & 63;
    float v = D[c*256 + a];
    DT[gid] = v;
    DTb[gid] = f2bu(v);
  }
}

// ---------------------------------------------------------------------------
// Implicit-GEMM conv (NCHW, 64x64 spatial, stride 1).  fp32 VALU (unchanged).
// res/out NOT __restrict__ (residual conv aliases res == out).
// ---------------------------------------------------------------------------
template<int KS, bool RELU, bool BIAS, bool RES>
__global__ __launch_bounds__(256) void k_conv(
    const float* __restrict__ in, const float* __restrict__ w,
    const float* __restrict__ bias, const float* res,
    float* out, int Cin, int Cout)
{
  const int K = Cin * KS * KS;
  __shared__ float As[32][64];
  __shared__ float Bs[32][68];
  const int tid = threadIdx.x;
  const int m0  = blockIdx.x * 64;
  const int n0  = blockIdx.y * 64;
  const int b   = m0 >> 12;
  const int hw0 = m0 & 4095;
  const int h   = hw0 >> 6;

  const int amm  = tid & 63;
  const int akk0 = tid >> 6;
  const int bkk  = tid & 31;
  const int bnn0 = tid >> 5;
  const int mmc  = (tid & 15) * 4;
  const int nnc  = (tid >> 4) * 4;

  float acc[4][4] = {};

  for (int kt = 0; kt < K; kt += 32) {
    #pragma unroll
    for (int i = 0; i < 8; ++i) {
      int kk = akk0 + i * 4;
      int k  = kt + kk;
      float v = 0.f;
      if (KS == 3) {
        int c  = k / 9;
        int r  = k - c * 9;
        int r3 = r / 3;
        int hh = h + r3 - 1;
        int ww = amm + (r - r3 * 3) - 1;
        if ((unsigned)hh < 64u && (unsigned)ww < 64u)
          v = in[((b * Cin + c) << 12) + (hh << 6) + ww];
      } else {
        v = in[((b * Cin + (kt + kk)) << 12) + hw0 + amm];
      }
      if (RELU) v = fmaxf(v, 0.f);
      As[kk][amm] = v;
    }
    #pragma unroll
    for (int i = 0; i < 8; ++i) {
      int nn = bnn0 + i * 8;
      Bs[bkk][nn] = w[(n0 + nn) * K + kt + bkk];
    }
    __syncthreads();
    #pragma unroll
    for (int kk = 0; kk < 32; ++kk) {
      float4 a4 = *(const float4*)(&As[kk][mmc]);
      float4 b4 = *(const float4*)(&Bs[kk][nnc]);
      FMA16(acc, a4, b4);
    }
    __syncthreads();
  }

  #pragma unroll
  for (int j2 = 0; j2 < 4; ++j2) {
    int n = n0 + nnc + j2;
    float bv = 0.f;
    if (BIAS) bv = bias[n];
    int base = ((b * Cout + n) << 12) + hw0 + mmc;
    float4 o4;
    o4.x = acc[0][j2] + bv; o4.y = acc[1][j2] + bv;
    o4.z = acc[2][j2] + bv; o4.w = acc[3][j2] + bv;
    if (RES) {
      float4 r4 = *(const float4*)(res + base);
      o4.x += r4.x; o4.y += r4.y; o4.z += r4.z; o4.w += r4.w;
    }
    *(float4*)(out + base) = o4;
  }
}

// ---------------------------------------------------------------------------
// CBAM (unchanged)
// ---------------------------------------------------------------------------
__global__ void k_pool(const float* __restrict__ l, float* __restrict__ avg,
                       float* __restrict__ mx){
  int b = blockIdx.y, a = blockIdx.x, tid = threadIdx.x;
  const float* p = l + ((size_t)(b * 256 + a) << 12);
  float s = 0.f, m = -1e30f;
  for (int i = tid; i < 4096; i += 256) { float v = p[i]; s += v; m = fmaxf(m, v); }
  __shared__ float ss[256], sm[256];
  ss[tid] = s; sm[tid] = m; __syncthreads();
  for (int o = 128; o > 0; o >>= 1) {
    if (tid < o) { ss[tid] += ss[tid+o]; sm[tid] = fmaxf(sm[tid], sm[tid+o]); }
    __syncthreads();
  }
  if (tid == 0) { avg[b*256+a] = ss[0] * (1.f/4096.f); mx[b*256+a] = sm[0]; }
}

__global__ void k_ca(const float* __restrict__ avg, const float* __restrict__ mx,
                     const float* __restrict__ w1, const float* __restrict__ w2,
                     float* __restrict__ cscale){
  int b = blockIdx.x, tid = threadIdx.x;
  __shared__ float h[16];
  if (tid < 16) {
    float sa = 0.f, sm = 0.f;
    for (int a = 0; a < 256; ++a) {
      float w = w1[tid*256 + a];
      sa += avg[b*256 + a] * w;
      sm += mx[b*256 + a] * w;
    }
    h[tid] = fmaxf(sa, 0.f) + fmaxf(sm, 0.f);
  }
  __syncthreads();
  float s = 0.f;
  for (int j = 0; j < 16; ++j) s += h[j] * w2[tid*16 + j];
  cscale[b*256 + tid] = 1.f / (1.f + __expf(-s));
}

__global__ void k_s2(const float* __restrict__ l, const float* __restrict__ cscale,
                     float* __restrict__ s2){
  int b = blockIdx.y;
  int hw = blockIdx.x * 256 + threadIdx.x;
  const float* p  = l + (((size_t)b * 256) << 12) + hw;
  const float* cs = cscale + b * 256;
  float s = 0.f, m = -1e30f;
  for (int a = 0; a < 256; ++a) {
    float v = p[(size_t)a << 12] * cs[a];
    s += v; m = fmaxf(m, v);
  }
  s2[((b*2) << 12) + hw]   = s * (1.f/256.f);
  s2[((b*2+1) << 12) + hw] = m;
}

__global__ void k_sa(const float* __restrict__ s2, const float* __restrict__ w,
                     float* __restrict__ sa){
  int b = blockIdx.y;
  int hw = blockIdx.x * 256 + threadIdx.x;
  int h = hw >> 6, ww = hw & 63;
  float acc = 0.f;
  for (int ch = 0; ch < 2; ++ch)
    for (int dh = -1; dh <= 1; ++dh)
      for (int dw = -1; dw <= 1; ++dw) {
        int hh = h + dh, wc = ww + dw;
        if ((unsigned)hh < 64u && (unsigned)wc < 64u)
          acc += s2[((b*2+ch) << 12) + (hh << 6) + wc] * w[ch*9 + (dh+1)*3 + (dw+1)];
      }
  sa[(b << 12) + hw] = 1.f / (1.f + __expf(-acc));
}

// lam[p][a] = l[b][a][hw]*csc[b][a]*sa[b][hw]/L
__global__ void k_lam_naive(const float* __restrict__ l, const float* __restrict__ cscale,
                            const float* __restrict__ sa, const float* __restrict__ Lb,
                            float* __restrict__ lam){
  int gid = blockIdx.x * 256 + threadIdx.x;          // p*256 + a
  if (gid >= 8388608) return;
  float invL = 1.0f / Lb[0];
  int a  = gid & 255;
  int p  = gid >> 8;
  int b  = p >> 12;
  int hw = p & 4095;
  float v = l[((size_t)(b*256 + a) << 12) + hw] * cscale[b*256 + a]
          * sa[(b << 12) + hw];
  lam[gid] = v * invL;
}

// ---------------------------------------------------------------------------
// FUSED LISTA: per block = 32 rows x all 16 iterations, bf16 MFMA Gram product.
//   y = x@Dict (in-kernel MFMA), z fp32 state in registers,
//   z_{i+1} = soft(z + (y - z@G)/L, lam);  z@S == z - z@G/L  (S symmetric).
// MFMA 16x16x32 bf16.  A: m=lane&15, k=quad*8+j.  B: n=lane&15, k=quad*8+j
// (G symmetric -> B-fragment = contiguous row read).  D: col=lane&15,
// row=quad*4+reg  [verified layouts: learn_hip m89/m120].
// ---------------------------------------------------------------------------
#define ZBS 272   // zb row stride (bf16 units): 16B-aligned, uniform bank use
#define XTS 80    // xTb row stride

__global__ __launch_bounds__(256, 2) void k_lista(
    const float* __restrict__ x,
    const unsigned short* __restrict__ DTb,
    const unsigned short* __restrict__ Gb,
    const float* __restrict__ lam, const float* __restrict__ Lb,
    float* __restrict__ zout)
{
  __shared__ unsigned short xTb[32][XTS];
  __shared__ unsigned short zb[32][ZBS];

  const int tid = threadIdx.x;
  const int m0  = blockIdx.x * 32;       // 32 rows, never crosses batch (4096%32==0)
  const int b   = m0 >> 12;
  const int hw0 = m0 & 4095;
  const float invL = 1.0f / Lb[0];

  // stage x^T as bf16: xTb[i][c] = x[b][c][hw0+i]
  {
    const int i  = tid & 31;
    const int c0 = tid >> 5;             // 0..7
    #pragma unroll
    for (int cc = 0; cc < 8; ++cc) {
      int c = c0 + cc * 8;
      xTb[i][c] = f2bu(x[((b * 64 + c) << 12) + hw0 + i]);
    }
  }
  __syncthreads();

  const int w   = tid >> 6;              // wave 0..3 -> col-tiles w*64..w*64+63
  const int ln  = tid & 63;
  const int q   = ln >> 4;
  const int l16 = ln & 15;

  float z[8][4], yl[8][4], lamr[8][4];

  // ---- y = x @ Dict  (K=64, two MFMA k-steps);  z0 = soft(y, lam)
  #pragma unroll
  for (int ct = 0; ct < 4; ++ct) {
    const int n0 = w * 64 + ct * 16;
    const short8v B0 = *(const short8v*)(DTb + (n0 + l16) * 64 + q * 8);
    const short8v B1 = *(const short8v*)(DTb + (n0 + l16) * 64 + 32 + q * 8);
    #pragma unroll
    for (int rt = 0; rt < 2; ++rt) {
      float4v a = {0.f, 0.f, 0.f, 0.f};
      const short8v A0 = *(const short8v*)(&xTb[rt * 16 + l16][q * 8]);
      const short8v A1 = *(const short8v*)(&xTb[rt * 16 + l16][32 + q * 8]);
      a = __builtin_amdgcn_mfma_f32_16x16x32_bf16(A0, B0, a, 0, 0, 0);
      a = __builtin_amdgcn_mfma_f32_16x16x32_bf16(A1, B1, a, 0, 0, 0);
      const int t = ct * 2 + rt;
      #pragma unroll
      for (int r = 0; r < 4; ++r) {
        const int row = rt * 16 + q * 4 + r;
        const int col = n0 + l16;
        const float lm = lam[(m0 + row) * 256 + col];
        const float yv = a[r];
        lamr[t][r] = lm;
        yl[t][r]   = yv * invL;
        const float z0 = softt(yv, lm);
        z[t][r] = z0;
        zb[row][col] = f2bu(z0);
      }
    }
  }
  __syncthreads();

  // ---- 16 in-block LISTA iterations
  for (int it = 0; it < 16; ++it) {
    float4v acc[8];
    #pragma unroll
    for (int ct = 0; ct < 4; ++ct) {
      const int n0 = w * 64 + ct * 16;
      short8v Bf[8];
      #pragma unroll
      for (int ks = 0; ks < 8; ++ks)
        Bf[ks] = *(const short8v*)(Gb + (n0 + l16) * 256 + ks * 32 + q * 8);
      #pragma unroll
      for (int rt = 0; rt < 2; ++rt) {
        float4v a = {0.f, 0.f, 0.f, 0.f};
        #pragma unroll
        for (int ks = 0; ks < 8; ++ks) {
          const short8v A = *(const short8v*)(&zb[rt * 16 + l16][ks * 32 + q * 8]);
          a = __builtin_amdgcn_mfma_f32_16x16x32_bf16(A, Bf[ks], a, 0, 0, 0);
        }
        acc[ct * 2 + rt] = a;
      }
    }
    __syncthreads();                       // all zb reads done
    #pragma unroll
    for (int t = 0; t < 8; ++t) {
      const int ct = t >> 1, rt = t & 1;
      const int n0 = w * 64 + ct * 16;
      #pragma unroll
      for (int r = 0; r < 4; ++r) {
        const int row = rt * 16 + q * 4 + r;
        const float nz = softt(z[t][r] + yl[t][r] - acc[t][r] * invL, lamr[t][r]);
        z[t][r] = nz;
        zb[row][n0 + l16] = f2bu(nz);
      }
    }
    __syncthreads();                       // zb writes visible
  }

  // ---- final z (fp32) to global [p][a]
  #pragma unroll
  for (int t = 0; t < 8; ++t) {
    const int ct = t >> 1, rt = t & 1;
    const int n0 = w * 64 + ct * 16;
    #pragma unroll
    for (int r = 0; r < 4; ++r) {
      const int row = rt * 16 + q * 4 + r;
      zout[(size_t)(m0 + row) * 256 + n0 + l16] = z[t][r];
    }
  }
}

// x_recon[p][c] = sum_a z[p][a] * DT[a][c]  -> f32 NCHW output
__global__ __launch_bounds__(256) void k_recon_simple(
    const float* __restrict__ z, const float* __restrict__ DT,
    float* __restrict__ out1)
{
  __shared__ float zs[16][256];
  const int tid = threadIdx.x;
  const int r0  = blockIdx.x * 16;
  const int b   = r0 >> 12;
  const int hw0 = r0 & 4095;

  for (int idx = tid; idx < 4096; idx += 256) {
    int r = idx >> 8, k = idx & 255;
    zs[r][k] = z[(r0 + r) * 256 + k];
  }
  __syncthreads();

  const int c  = tid & 63;
  const int rg = tid >> 6;
  float acc[4] = {0.f, 0.f, 0.f, 0.f};
  for (int a = 0; a < 256; ++a) {
    float d = DT[a * 64 + c];
    #pragma unroll
    for (int i = 0; i < 4; ++i) acc[i] += zs[rg + 4*i][a] * d;
  }
  #pragma unroll
  for (int i = 0; i < 4; ++i) {
    int r = rg + 4*i;
    out1[((b * 64 + c) << 12) + hw0 + r] = acc[i];
  }
}

// z [p][a] fp32 -> out0 f32 [b][a][hw]
__global__ void k_zout_f32(const float* __restrict__ z, float* __restrict__ out0){
  int gid = blockIdx.x * 256 + threadIdx.x;   // (b*256 + a)*4096 + hw
  if (gid >= 8388608) return;
  int b  = gid >> 20;
  int a  = (gid >> 12) & 255;
  int hw = gid & 4095;
  out0[gid] = z[((size_t)((b << 12) + hw)) * 256 + a];
}

// Dict passthrough -> f32 output
__global__ void k_dictout_f32(const float* __restrict__ D, float* __restrict__ out2){
  int i = blockIdx.x * 256 + threadIdx.x;
  if (i < 16384) out2[i] = D[i];
}

// ---------------------------------------------------------------------------
extern "C" void kernel_launch(void* const* d_in, const int* in_sizes, int n_in,
                              void* d_out, int out_size, void* d_ws, size_t ws_size,
                              hipStream_t stream)
{
  (void)in_sizes; (void)n_in; (void)out_size; (void)ws_size;

  const float* x    = (const float*)d_in[0];
  const float* cw   = (const float*)d_in[1];
  const float* cb   = (const float*)d_in[2];
  const float* r1w1 = (const float*)d_in[3];
  const float* r1w2 = (const float*)d_in[4];
  const float* r2w1 = (const float*)d_in[5];
  const float* r2w2 = (const float*)d_in[6];
  const float* caw1 = (const float*)d_in[7];
  const float* caw2 = (const float*)d_in[8];
  const float* saw  = (const float*)d_in[9];
  const float* D    = (const float*)d_in[10];
  const float* Lsrc = (const float*)d_in[11];

  float* p = (float*)d_ws;
  float* DT   = p; p += 16384;
  float* Lb   = p; p += 8;
  unsigned short* Gb  = (unsigned short*)p; p += 32768;   // 65536 bf16
  unsigned short* DTb = (unsigned short*)p; p += 8192;    // 16384 bf16
  float* avg  = p; p += 2048;
  float* mx   = p; p += 2048;
  float* csc  = p; p += 2048;
  float* s2   = p; p += 65536;
  float* sa   = p; p += 32768;
  float* l    = p; p += 8388608;
  float* lam  = p; p += 8388608;
  float* zt   = p; p += 8388608;   // conv temp t, then final z
  float* t    = zt;
  float* z    = zt;

  float* out0 = (float*)d_out;               // z       [8,256,64,64]
  float* out1 = out0 + (size_t)8*256*4096;   // x_recon [8,64,64,64]
  float* out2 = out1 + (size_t)8*64*4096;    // Dict    [64,256]

  dim3 b256(256);

  k_Lin<<<dim3(1), dim3(1), 0, stream>>>(Lsrc, Lb);
  k_gram<<<dim3(256), b256, 0, stream>>>(D, Gb);
  k_transpD<<<dim3(64), b256, 0, stream>>>(D, DT, DTb);

  // conv trunk (fp32, unchanged this round)
  k_conv<3, false, true, false><<<dim3(512, 4), b256, 0, stream>>>(
      x, cw, cb, (const float*)nullptr, l, 64, 256);
  k_conv<3, true, false, false><<<dim3(512, 2), b256, 0, stream>>>(
      l, r1w1, (const float*)nullptr, (const float*)nullptr, t, 256, 128);
  k_conv<1, true, false, true><<<dim3(512, 4), b256, 0, stream>>>(
      t, r1w2, (const float*)nullptr, l, l, 128, 256);
  k_conv<3, true, false, false><<<dim3(512, 2), b256, 0, stream>>>(
      l, r2w1, (const float*)nullptr, (const float*)nullptr, t, 256, 128);
  k_conv<1, true, false, true><<<dim3(512, 4), b256, 0, stream>>>(
      t, r2w2, (const float*)nullptr, l, l, 128, 256);

  // CBAM
  k_pool<<<dim3(256, 8), b256, 0, stream>>>(l, avg, mx);
  k_ca<<<dim3(8), b256, 0, stream>>>(avg, mx, caw1, caw2, csc);
  k_s2<<<dim3(16, 8), b256, 0, stream>>>(l, csc, s2);
  k_sa<<<dim3(16, 8), b256, 0, stream>>>(s2, saw, sa);
  k_lam_naive<<<dim3(32768), b256, 0, stream>>>(l, csc, sa, Lb, lam);

  // FUSED LISTA: y-GEMM + 16 iterations + z writeback, one launch
  k_lista<<<dim3(1024), b256, 0, stream>>>(x, DTb, Gb, lam, Lb, z);

  // outputs (float32)
  k_recon_simple<<<dim3(2048), b256, 0, stream>>>(z, DT, out1);
  k_zout_f32<<<dim3(32768), b256, 0, stream>>>(z, out0);
  k_dictout_f32<<<dim3(64), b256, 0, stream>>>(D, out2);
}

// Round 8
// 935.444 us; speedup vs baseline: 2.8466x; 1.4474x over previous
//
#include <hip/hip_runtime.h>
#include <hip/hip_bf16.h>

typedef __attribute__((ext_vector_type(8))) short short8v;
typedef __attribute__((ext_vector_type(4))) float float4v;

__device__ __forceinline__ unsigned short f2bu(float v){
  __hip_bfloat16 h = __float2bfloat16(v);
  union { __hip_bfloat16 h; unsigned short u; } cv; cv.h = h; return cv.u;
}

// soft(v, lam) = sign(v) * max(|v| - lam, 0)   (lam may be negative)
__device__ __forceinline__ float softt(float v, float lam){
  float t = fabsf(v) - lam;
  float sg = (v > 0.f) ? 1.f : ((v < 0.f) ? -1.f : 0.f);
  return (t > 0.f) ? sg * t : 0.f;
}

// L scalar (f32 input)
__global__ void k_Lin(const float* __restrict__ Lsrc, float* __restrict__ Lb){
  Lb[0] = Lsrc[0];
}

// Gram in bf16: Gb[j][a] = bf16(sum_c D[c][j]*D[c][a]).  Diagonal == 1 exactly.
__global__ void k_gram(const float* __restrict__ D, unsigned short* __restrict__ Gb){
  int j = blockIdx.x, a = threadIdx.x;
  float acc = 0.f;
  for (int c = 0; c < 64; ++c)
    acc += D[c*256 + j] * D[c*256 + a];
  Gb[j*256 + a] = f2bu(acc);
}

// DT[a][c] = D[c][a] (f32 for recon) + bf16 copy (B-fragments of y-GEMM)
__global__ void k_transpD(const float* __restrict__ D, float* __restrict__ DT,
                          unsigned short* __restrict__ DTb){
  int gid = blockIdx.x * 256 + threadIdx.x;     // gid = a*64 + c
  if (gid < 16384) {
    int a = gid >> 6, c = gid & 63;
    float v = D[c*256 + a];
    DT[gid] = v;
    DTb[gid] = f2bu(v);
  }
}

// fp32 -> bf16 cast (conv weights)
__global__ void k_castw(const float* __restrict__ w, unsigned short* __restrict__ wb,
                        int n){
  int gid = blockIdx.x * 256 + threadIdx.x;
  if (gid < n) wb[gid] = f2bu(w[gid]);
}

// ---------------------------------------------------------------------------
// MFMA implicit-GEMM conv (NCHW, 64x64 spatial, stride 1), bf16 inputs/weights,
// fp32 accumulate.  BM=64 (one image row), BN=128, BK=32, 256 threads/4 waves.
// Fragment layouts as verified by k_lista (round 7, HW-passed):
//   A: m=lane&15, k=quad*8+j;  B: n=lane&15, k=quad*8+j;
//   C/D: col=lane&15, row=quad*4+reg.
// Weight bf16 buffer wb is OIHW flat [Cout][K], K=Cin*KS*KS, k-contiguous.
// res/out NOT __restrict__ (residual conv aliases res == out).
// ---------------------------------------------------------------------------
template<int KS, bool RELU, bool BIAS, bool RES>
__global__ __launch_bounds__(256) void k_conv_mfma(
    const float* __restrict__ in, const unsigned short* __restrict__ wb,
    const float* __restrict__ bias, const float* res,
    float* out, int Cin, int Cout)
{
  const int K = Cin * KS * KS;
  __shared__ unsigned short Asb[64][40];    // row stride 80 B (16B-aligned chunks)
  __shared__ unsigned short Bsb[128][40];

  const int tid = threadIdx.x;
  const int m0  = blockIdx.x * 64;          // 64 positions = one image row
  const int n0  = blockIdx.y * 128;
  const int b   = m0 >> 12;
  const int hw0 = m0 & 4095;
  const int h   = hw0 >> 6;

  // staging assignments
  const int sm = tid & 63;                  // A row (m)
  const int sq = tid >> 6;                  // A chunk 0..3
  const int bn = tid & 127;                 // B row (n-local)
  const int bq = tid >> 7;                  // 0..1 -> chunks bq*2, bq*2+1

  // MFMA lane mapping
  const int w   = tid >> 6;                 // wave 0..3 -> n-range w*32..+32
  const int ln  = tid & 63;
  const int q   = ln >> 4;
  const int l16 = ln & 15;

  float4v acc[2][4];
  #pragma unroll
  for (int nt = 0; nt < 2; ++nt)
    #pragma unroll
    for (int mt = 0; mt < 4; ++mt)
      acc[nt][mt] = (float4v){0.f, 0.f, 0.f, 0.f};

  for (int kt = 0; kt < K; kt += 32) {
    // ---- A stage: one b128 write per thread
    {
      short av[8];
      #pragma unroll
      for (int j = 0; j < 8; ++j) {
        int k = kt + sq * 8 + j;
        float v = 0.f;
        if (KS == 3) {
          int c  = k / 9;
          int r  = k - c * 9;
          int r3 = r / 3;
          int hh = h + r3 - 1;
          int ww = sm + (r - r3 * 3) - 1;
          if ((unsigned)hh < 64u && (unsigned)ww < 64u)
            v = in[((b * Cin + c) << 12) + (hh << 6) + ww];
        } else {
          v = in[((b * Cin + k) << 12) + hw0 + sm];
        }
        if (RELU) v = fmaxf(v, 0.f);
        av[j] = (short)f2bu(v);
      }
      *(short8v*)(&Asb[sm][sq * 8]) =
          (short8v){av[0],av[1],av[2],av[3],av[4],av[5],av[6],av[7]};
    }
    // ---- B stage: two b128 copies per thread (wb rows are k-contiguous)
    #pragma unroll
    for (int i = 0; i < 2; ++i) {
      int ch = bq * 2 + i;
      *(short8v*)(&Bsb[bn][ch * 8]) =
          *(const short8v*)(wb + (size_t)(n0 + bn) * K + kt + ch * 8);
    }
    __syncthreads();
    // ---- MFMA
    short8v Af[4];
    #pragma unroll
    for (int mt = 0; mt < 4; ++mt)
      Af[mt] = *(const short8v*)(&Asb[mt * 16 + l16][q * 8]);
    #pragma unroll
    for (int nt = 0; nt < 2; ++nt) {
      short8v Bf = *(const short8v*)(&Bsb[w * 32 + nt * 16 + l16][q * 8]);
      #pragma unroll
      for (int mt = 0; mt < 4; ++mt)
        acc[nt][mt] = __builtin_amdgcn_mfma_f32_16x16x32_bf16(
            Af[mt], Bf, acc[nt][mt], 0, 0, 0);
    }
    __syncthreads();
  }

  // ---- epilogue: C row=q*4+r (spatial m), col=l16 (n)
  #pragma unroll
  for (int nt = 0; nt < 2; ++nt) {
    const int n = n0 + w * 32 + nt * 16 + l16;
    float bv = 0.f;
    if (BIAS) bv = bias[n];
    #pragma unroll
    for (int mt = 0; mt < 4; ++mt) {
      const int base = ((b * Cout + n) << 12) + hw0 + mt * 16 + q * 4;
      float4 o4;
      o4.x = acc[nt][mt][0] + bv; o4.y = acc[nt][mt][1] + bv;
      o4.z = acc[nt][mt][2] + bv; o4.w = acc[nt][mt][3] + bv;
      if (RES) {
        float4 r4 = *(const float4*)(res + base);
        o4.x += r4.x; o4.y += r4.y; o4.z += r4.z; o4.w += r4.w;
      }
      *(float4*)(out + base) = o4;
    }
  }
}

// ---------------------------------------------------------------------------
// CBAM (unchanged)
// ---------------------------------------------------------------------------
__global__ void k_pool(const float* __restrict__ l, float* __restrict__ avg,
                       float* __restrict__ mx){
  int b = blockIdx.y, a = blockIdx.x, tid = threadIdx.x;
  const float* p = l + ((size_t)(b * 256 + a) << 12);
  float s = 0.f, m = -1e30f;
  for (int i = tid; i < 4096; i += 256) { float v = p[i]; s += v; m = fmaxf(m, v); }
  __shared__ float ss[256], sm[256];
  ss[tid] = s; sm[tid] = m; __syncthreads();
  for (int o = 128; o > 0; o >>= 1) {
    if (tid < o) { ss[tid] += ss[tid+o]; sm[tid] = fmaxf(sm[tid], sm[tid+o]); }
    __syncthreads();
  }
  if (tid == 0) { avg[b*256+a] = ss[0] * (1.f/4096.f); mx[b*256+a] = sm[0]; }
}

__global__ void k_ca(const float* __restrict__ avg, const float* __restrict__ mx,
                     const float* __restrict__ w1, const float* __restrict__ w2,
                     float* __restrict__ cscale){
  int b = blockIdx.x, tid = threadIdx.x;
  __shared__ float h[16];
  if (tid < 16) {
    float sa = 0.f, sm = 0.f;
    for (int a = 0; a < 256; ++a) {
      float w = w1[tid*256 + a];
      sa += avg[b*256 + a] * w;
      sm += mx[b*256 + a] * w;
    }
    h[tid] = fmaxf(sa, 0.f) + fmaxf(sm, 0.f);
  }
  __syncthreads();
  float s = 0.f;
  for (int j = 0; j < 16; ++j) s += h[j] * w2[tid*16 + j];
  cscale[b*256 + tid] = 1.f / (1.f + __expf(-s));
}

__global__ void k_s2(const float* __restrict__ l, const float* __restrict__ cscale,
                     float* __restrict__ s2){
  int b = blockIdx.y;
  int hw = blockIdx.x * 256 + threadIdx.x;
  const float* p  = l + (((size_t)b * 256) << 12) + hw;
  const float* cs = cscale + b * 256;
  float s = 0.f, m = -1e30f;
  for (int a = 0; a < 256; ++a) {
    float v = p[(size_t)a << 12] * cs[a];
    s += v; m = fmaxf(m, v);
  }
  s2[((b*2) << 12) + hw]   = s * (1.f/256.f);
  s2[((b*2+1) << 12) + hw] = m;
}

__global__ void k_sa(const float* __restrict__ s2, const float* __restrict__ w,
                     float* __restrict__ sa){
  int b = blockIdx.y;
  int hw = blockIdx.x * 256 + threadIdx.x;
  int h = hw >> 6, ww = hw & 63;
  float acc = 0.f;
  for (int ch = 0; ch < 2; ++ch)
    for (int dh = -1; dh <= 1; ++dh)
      for (int dw = -1; dw <= 1; ++dw) {
        int hh = h + dh, wc = ww + dw;
        if ((unsigned)hh < 64u && (unsigned)wc < 64u)
          acc += s2[((b*2+ch) << 12) + (hh << 6) + wc] * w[ch*9 + (dh+1)*3 + (dw+1)];
      }
  sa[(b << 12) + hw] = 1.f / (1.f + __expf(-acc));
}

// lam[p][a] = l[b][a][hw]*csc[b][a]*sa[b][hw]/L
__global__ void k_lam_naive(const float* __restrict__ l, const float* __restrict__ cscale,
                            const float* __restrict__ sa, const float* __restrict__ Lb,
                            float* __restrict__ lam){
  int gid = blockIdx.x * 256 + threadIdx.x;          // p*256 + a
  if (gid >= 8388608) return;
  float invL = 1.0f / Lb[0];
  int a  = gid & 255;
  int p  = gid >> 8;
  int b  = p >> 12;
  int hw = p & 4095;
  float v = l[((size_t)(b*256 + a) << 12) + hw] * cscale[b*256 + a]
          * sa[(b << 12) + hw];
  lam[gid] = v * invL;
}

// ---------------------------------------------------------------------------
// FUSED LISTA (unchanged from round 7, HW-passed)
// ---------------------------------------------------------------------------
#define ZBS 272
#define XTS 80

__global__ __launch_bounds__(256, 2) void k_lista(
    const float* __restrict__ x,
    const unsigned short* __restrict__ DTb,
    const unsigned short* __restrict__ Gb,
    const float* __restrict__ lam, const float* __restrict__ Lb,
    float* __restrict__ zout)
{
  __shared__ unsigned short xTb[32][XTS];
  __shared__ unsigned short zb[32][ZBS];

  const int tid = threadIdx.x;
  const int m0  = blockIdx.x * 32;
  const int b   = m0 >> 12;
  const int hw0 = m0 & 4095;
  const float invL = 1.0f / Lb[0];

  {
    const int i  = tid & 31;
    const int c0 = tid >> 5;
    #pragma unroll
    for (int cc = 0; cc < 8; ++cc) {
      int c = c0 + cc * 8;
      xTb[i][c] = f2bu(x[((b * 64 + c) << 12) + hw0 + i]);
    }
  }
  __syncthreads();

  const int w   = tid >> 6;
  const int ln  = tid & 63;
  const int q   = ln >> 4;
  const int l16 = ln & 15;

  float z[8][4], yl[8][4], lamr[8][4];

  #pragma unroll
  for (int ct = 0; ct < 4; ++ct) {
    const int n0 = w * 64 + ct * 16;
    const short8v B0 = *(const short8v*)(DTb + (n0 + l16) * 64 + q * 8);
    const short8v B1 = *(const short8v*)(DTb + (n0 + l16) * 64 + 32 + q * 8);
    #pragma unroll
    for (int rt = 0; rt < 2; ++rt) {
      float4v a = {0.f, 0.f, 0.f, 0.f};
      const short8v A0 = *(const short8v*)(&xTb[rt * 16 + l16][q * 8]);
      const short8v A1 = *(const short8v*)(&xTb[rt * 16 + l16][32 + q * 8]);
      a = __builtin_amdgcn_mfma_f32_16x16x32_bf16(A0, B0, a, 0, 0, 0);
      a = __builtin_amdgcn_mfma_f32_16x16x32_bf16(A1, B1, a, 0, 0, 0);
      const int t = ct * 2 + rt;
      #pragma unroll
      for (int r = 0; r < 4; ++r) {
        const int row = rt * 16 + q * 4 + r;
        const int col = n0 + l16;
        const float lm = lam[(m0 + row) * 256 + col];
        const float yv = a[r];
        lamr[t][r] = lm;
        yl[t][r]   = yv * invL;
        const float z0 = softt(yv, lm);
        z[t][r] = z0;
        zb[row][col] = f2bu(z0);
      }
    }
  }
  __syncthreads();

  for (int it = 0; it < 16; ++it) {
    float4v acc[8];
    #pragma unroll
    for (int ct = 0; ct < 4; ++ct) {
      const int n0 = w * 64 + ct * 16;
      short8v Bf[8];
      #pragma unroll
      for (int ks = 0; ks < 8; ++ks)
        Bf[ks] = *(const short8v*)(Gb + (n0 + l16) * 256 + ks * 32 + q * 8);
      #pragma unroll
      for (int rt = 0; rt < 2; ++rt) {
        float4v a = {0.f, 0.f, 0.f, 0.f};
        #pragma unroll
        for (int ks = 0; ks < 8; ++ks) {
          const short8v A = *(const short8v*)(&zb[rt * 16 + l16][ks * 32 + q * 8]);
          a = __builtin_amdgcn_mfma_f32_16x16x32_bf16(A, Bf[ks], a, 0, 0, 0);
        }
        acc[ct * 2 + rt] = a;
      }
    }
    __syncthreads();
    #pragma unroll
    for (int t = 0; t < 8; ++t) {
      const int ct = t >> 1, rt = t & 1;
      const int n0 = w * 64 + ct * 16;
      #pragma unroll
      for (int r = 0; r < 4; ++r) {
        const int row = rt * 16 + q * 4 + r;
        const float nz = softt(z[t][r] + yl[t][r] - acc[t][r] * invL, lamr[t][r]);
        z[t][r] = nz;
        zb[row][n0 + l16] = f2bu(nz);
      }
    }
    __syncthreads();
  }

  #pragma unroll
  for (int t = 0; t < 8; ++t) {
    const int ct = t >> 1, rt = t & 1;
    const int n0 = w * 64 + ct * 16;
    #pragma unroll
    for (int r = 0; r < 4; ++r) {
      const int row = rt * 16 + q * 4 + r;
      zout[(size_t)(m0 + row) * 256 + n0 + l16] = z[t][r];
    }
  }
}

// x_recon[p][c] = sum_a z[p][a] * DT[a][c]  -> f32 NCHW output
__global__ __launch_bounds__(256) void k_recon_simple(
    const float* __restrict__ z, const float* __restrict__ DT,
    float* __restrict__ out1)
{
  __shared__ float zs[16][256];
  const int tid = threadIdx.x;
  const int r0  = blockIdx.x * 16;
  const int b   = r0 >> 12;
  const int hw0 = r0 & 4095;

  for (int idx = tid; idx < 4096; idx += 256) {
    int r = idx >> 8, k = idx & 255;
    zs[r][k] = z[(r0 + r) * 256 + k];
  }
  __syncthreads();

  const int c  = tid & 63;
  const int rg = tid >> 6;
  float acc[4] = {0.f, 0.f, 0.f, 0.f};
  for (int a = 0; a < 256; ++a) {
    float d = DT[a * 64 + c];
    #pragma unroll
    for (int i = 0; i < 4; ++i) acc[i] += zs[rg + 4*i][a] * d;
  }
  #pragma unroll
  for (int i = 0; i < 4; ++i) {
    int r = rg + 4*i;
    out1[((b * 64 + c) << 12) + hw0 + r] = acc[i];
  }
}

// z [p][a] fp32 -> out0 f32 [b][a][hw]
__global__ void k_zout_f32(const float* __restrict__ z, float* __restrict__ out0){
  int gid = blockIdx.x * 256 + threadIdx.x;
  if (gid >= 8388608) return;
  int b  = gid >> 20;
  int a  = (gid >> 12) & 255;
  int hw = gid & 4095;
  out0[gid] = z[((size_t)((b << 12) + hw)) * 256 + a];
}

__global__ void k_dictout_f32(const float* __restrict__ D, float* __restrict__ out2){
  int i = blockIdx.x * 256 + threadIdx.x;
  if (i < 16384) out2[i] = D[i];
}

// ---------------------------------------------------------------------------
extern "C" void kernel_launch(void* const* d_in, const int* in_sizes, int n_in,
                              void* d_out, int out_size, void* d_ws, size_t ws_size,
                              hipStream_t stream)
{
  (void)in_sizes; (void)n_in; (void)out_size; (void)ws_size;

  const float* x    = (const float*)d_in[0];
  const float* cw   = (const float*)d_in[1];
  const float* cb   = (const float*)d_in[2];
  const float* r1w1 = (const float*)d_in[3];
  const float* r1w2 = (const float*)d_in[4];
  const float* r2w1 = (const float*)d_in[5];
  const float* r2w2 = (const float*)d_in[6];
  const float* caw1 = (const float*)d_in[7];
  const float* caw2 = (const float*)d_in[8];
  const float* saw  = (const float*)d_in[9];
  const float* D    = (const float*)d_in[10];
  const float* Lsrc = (const float*)d_in[11];

  float* p = (float*)d_ws;
  float* DT   = p; p += 16384;
  float* Lb   = p; p += 8;
  unsigned short* Gb  = (unsigned short*)p; p += 32768;   // 65536 bf16
  unsigned short* DTb = (unsigned short*)p; p += 8192;    // 16384 bf16
  unsigned short* cwb   = (unsigned short*)p; p += 73728;   // 147456 bf16
  unsigned short* r1w1b = (unsigned short*)p; p += 147456;  // 294912 bf16
  unsigned short* r1w2b = (unsigned short*)p; p += 16384;   // 32768 bf16
  unsigned short* r2w1b = (unsigned short*)p; p += 147456;
  unsigned short* r2w2b = (unsigned short*)p; p += 16384;
  float* avg  = p; p += 2048;
  float* mx   = p; p += 2048;
  float* csc  = p; p += 2048;
  float* s2   = p; p += 65536;
  float* sa   = p; p += 32768;
  float* l    = p; p += 8388608;
  float* lam  = p; p += 8388608;
  float* zt   = p; p += 8388608;   // conv temp t, then final z
  float* t    = zt;
  float* z    = zt;

  float* out0 = (float*)d_out;               // z       [8,256,64,64]
  float* out1 = out0 + (size_t)8*256*4096;   // x_recon [8,64,64,64]
  float* out2 = out1 + (size_t)8*64*4096;    // Dict    [64,256]

  dim3 b256(256);

  k_Lin<<<dim3(1), dim3(1), 0, stream>>>(Lsrc, Lb);
  k_gram<<<dim3(256), b256, 0, stream>>>(D, Gb);
  k_transpD<<<dim3(64), b256, 0, stream>>>(D, DT, DTb);
  k_castw<<<dim3(576),  b256, 0, stream>>>(cw,   cwb,   147456);
  k_castw<<<dim3(1152), b256, 0, stream>>>(r1w1, r1w1b, 294912);
  k_castw<<<dim3(128),  b256, 0, stream>>>(r1w2, r1w2b, 32768);
  k_castw<<<dim3(1152), b256, 0, stream>>>(r2w1, r2w1b, 294912);
  k_castw<<<dim3(128),  b256, 0, stream>>>(r2w2, r2w2b, 32768);

  // conv trunk (bf16 MFMA)
  k_conv_mfma<3, false, true, false><<<dim3(512, 2), b256, 0, stream>>>(
      x, cwb, cb, (const float*)nullptr, l, 64, 256);
  k_conv_mfma<3, true, false, false><<<dim3(512, 1), b256, 0, stream>>>(
      l, r1w1b, (const float*)nullptr, (const float*)nullptr, t, 256, 128);
  k_conv_mfma<1, true, false, true><<<dim3(512, 2), b256, 0, stream>>>(
      t, r1w2b, (const float*)nullptr, l, l, 128, 256);
  k_conv_mfma<3, true, false, false><<<dim3(512, 1), b256, 0, stream>>>(
      l, r2w1b, (const float*)nullptr, (const float*)nullptr, t, 256, 128);
  k_conv_mfma<1, true, false, true><<<dim3(512, 2), b256, 0, stream>>>(
      t, r2w2b, (const float*)nullptr, l, l, 128, 256);

  // CBAM
  k_pool<<<dim3(256, 8), b256, 0, stream>>>(l, avg, mx);
  k_ca<<<dim3(8), b256, 0, stream>>>(avg, mx, caw1, caw2, csc);
  k_s2<<<dim3(16, 8), b256, 0, stream>>>(l, csc, s2);
  k_sa<<<dim3(16, 8), b256, 0, stream>>>(s2, saw, sa);
  k_lam_naive<<<dim3(32768), b256, 0, stream>>>(l, csc, sa, Lb, lam);

  // FUSED LISTA
  k_lista<<<dim3(1024), b256, 0, stream>>>(x, DTb, Gb, lam, Lb, z);

  // outputs (float32)
  k_recon_simple<<<dim3(2048), b256, 0, stream>>>(z, DT, out1);
  k_zout_f32<<<dim3(32768), b256, 0, stream>>>(z, out0);
  k_dictout_f32<<<dim3(64), b256, 0, stream>>>(D, out2);
}